// Round 10
// baseline (666.071 us; speedup 1.0000x reference)
//
#include <hip/hip_runtime.h>
#include <hip/hip_bf16.h>
#include <math.h>

// GPT forward: V=50257, B=16, T=256, D=64, H=4, HS=16, L=4, F=256
constexpr int NV  = 50257;
constexpr int NB  = 16;
constexpr int NT  = 256;
constexpr int ND  = 64;
constexpr int NH  = 4;
constexpr int NHS = 16;
constexpr int NL  = 4;
constexpr int NF  = 256;
constexpr int NN  = NB * NT;        // 4096 rows
constexpr float EPS = 1e-5f;

constexpr int NSTEP = 50;                    // 1024-col steps
constexpr int NVP  = NSTEP * 1024;           // 51200 padded vocab
constexpr int LOGITS = NN * NV;              // 205,852,672

// workspace layout (float offsets)
constexpr int X_OFF   = 0;                        // [NN*ND]
constexpr int Q_OFF   = X_OFF  + NN * ND;
constexpr int K_OFF   = Q_OFF  + NN * ND;
constexpr int V_OFF   = K_OFF  + NN * ND;
constexpr int O_OFF   = V_OFF  + NN * ND;
constexpr int A_OFF   = O_OFF  + NN * ND;         // (spacer)
constexpr int XFB_OFF = A_OFF  + NN * NF;         // bf16 [NN*ND]
constexpr int WM_OFF  = XFB_OFF + NN * ND / 2;    // (spacer)
constexpr int WS2_OFF = WM_OFF + 200 * NN;        // [NSTEP*NN] sum-exp partials
constexpr int WHB_OFF = WS2_OFF + 200 * NN;       // bf16 [NVP*64]
constexpr int LP_OFF  = WHB_OFF + NVP * 32;       // [NN]

typedef __bf16 bf16x8 __attribute__((ext_vector_type(8)));
typedef float  f32x4  __attribute__((ext_vector_type(4)));

// ---------------- embed + LN1 + QKV (layer 0 only; 16 rows/block, 256 blocks) ----------------
__global__ __launch_bounds__(256) void k_ln_qkv(
        float* __restrict__ x, const float* __restrict__ g, const float* __restrict__ bb,
        const float* __restrict__ Wq, const float* __restrict__ Wk, const float* __restrict__ Wv,
        float* __restrict__ q, float* __restrict__ k, float* __restrict__ v,
        const int* __restrict__ idx, const float* __restrict__ tok,
        const float* __restrict__ pos) {
    __shared__ float hs[16][65];
    int t = threadIdx.x;
    int r0 = blockIdx.x * 16;
    for (int i = t; i < 16 * 64; i += 256) {
        int n = r0 + (i >> 6);
        int tt = n & (NT - 1), d = i & 63;
        float e = tok[idx[n] * ND + d] + pos[tt * ND + d];
        hs[i >> 6][i & 63] = e;
        x[(size_t)r0 * 64 + i] = e;
    }
    __syncthreads();
    {
        int row = t >> 4, sub = t & 15;
        float s = 0.f, s2 = 0.f;
        #pragma unroll
        for (int j = 0; j < 4; j++) { float vv = hs[row][sub * 4 + j]; s += vv; s2 += vv * vv; }
        #pragma unroll
        for (int off = 1; off < 16; off <<= 1) { s += __shfl_xor(s, off); s2 += __shfl_xor(s2, off); }
        float mu = s * (1.f / 64.f);
        float var = s2 * (1.f / 64.f) - mu * mu;
        float rs = rsqrtf(var + EPS);
        #pragma unroll
        for (int j = 0; j < 4; j++) {
            int d = sub * 4 + j;
            hs[row][d] = (hs[row][d] - mu) * rs * g[d] + bb[d];
        }
    }
    __syncthreads();
    int c = t & 63, rg = t >> 6;
    int head = c >> 4, sidx = c & 15;
    float aq[4], ak[4], av[4];
    #pragma unroll
    for (int i = 0; i < 4; i++) { aq[i] = 0.f; ak[i] = 0.f; av[i] = 0.f; }
    for (int kk = 0; kk < 64; kk++) {
        float wq = Wq[(head * 64 + kk) * 16 + sidx];
        float wk = Wk[(head * 64 + kk) * 16 + sidx];
        float wv = Wv[(head * 64 + kk) * 16 + sidx];
        #pragma unroll
        for (int i = 0; i < 4; i++) {
            float h = hs[rg * 4 + i][kk];
            aq[i] += h * wq; ak[i] += h * wk; av[i] += h * wv;
        }
    }
    #pragma unroll
    for (int i = 0; i < 4; i++) {
        int n = r0 + rg * 4 + i;
        int b = n >> 8, tt = n & 255;
        int oidx = ((b * NH + head) * NT + tt) * NHS + sidx;
        q[oidx] = aq[i]; k[oidx] = ak[i]; v[oidx] = av[i];
    }
}

// ---------------- fused causal attention (split-u), 256 blocks ----------------
__global__ __launch_bounds__(256) void k_attn(
        const float* __restrict__ q, const float* __restrict__ k,
        const float* __restrict__ v, float* __restrict__ o) {
    __shared__ float ks[256][16];
    __shared__ float vs[256][16];
    int blk = blockIdx.x;
    int bh = blk >> 2;
    int tq = blk & 3;
    int t = threadIdx.x;
    int tl = t >> 2, sub = t & 3;
    int tt = tq * 64 + tl;
    int nrows = tq * 64 + 64;
    const float* kb = k + bh * NT * NHS;
    const float* vb = v + bh * NT * NHS;
    for (int i = t; i < nrows * 16; i += 256) {
        (&ks[0][0])[i] = kb[i];
        (&vs[0][0])[i] = vb[i];
    }
    __syncthreads();
    float qr[16];
    const float* qp = q + bh * NT * NHS + tt * NHS;
    #pragma unroll
    for (int j = 0; j < 16; j += 4) {
        float4 qv = *(const float4*)(qp + j);
        qr[j] = qv.x; qr[j+1] = qv.y; qr[j+2] = qv.z; qr[j+3] = qv.w;
    }
    float m = -1e30f, l = 0.f, acc[16];
    #pragma unroll
    for (int j = 0; j < 16; j++) acc[j] = 0.f;
    for (int u = sub; u <= tt; u += 4) {
        float s = 0.f;
        #pragma unroll
        for (int j = 0; j < 16; j++) s += qr[j] * ks[u][j];
        float mn = fmaxf(m, s);
        float corr = __expf(m - mn);
        float p = __expf(s - mn);
        l = l * corr + p;
        #pragma unroll
        for (int j = 0; j < 16; j++) acc[j] = acc[j] * corr + p * vs[u][j];
        m = mn;
    }
    #pragma unroll
    for (int off = 1; off < 4; off <<= 1) {
        float mo = __shfl_xor(m, off);
        float lo = __shfl_xor(l, off);
        float mn = fmaxf(m, mo);
        float c1 = __expf(m - mn), c2 = __expf(mo - mn);
        l = l * c1 + lo * c2;
        #pragma unroll
        for (int j = 0; j < 16; j++) {
            float ao = __shfl_xor(acc[j], off);
            acc[j] = acc[j] * c1 + ao * c2;
        }
        m = mn;
    }
    float inv = 1.f / l;
    int b = bh >> 2, h = bh & 3;
    float* op = o + (b * NT + tt) * ND + h * NHS;
    float o0, o1, o2, o3;
    if (sub == 0)      { o0 = acc[0];  o1 = acc[1];  o2 = acc[2];  o3 = acc[3];  }
    else if (sub == 1) { o0 = acc[4];  o1 = acc[5];  o2 = acc[6];  o3 = acc[7];  }
    else if (sub == 2) { o0 = acc[8];  o1 = acc[9];  o2 = acc[10]; o3 = acc[11]; }
    else               { o0 = acc[12]; o1 = acc[13]; o2 = acc[14]; o3 = acc[15]; }
    float4 ov = make_float4(o0 * inv, o1 * inv, o2 * inv, o3 * inv);
    *(float4*)(op + sub * 4) = ov;
}

// ---------------- proj+res+LN2+MLP1+MLP2+res, then NEXT-layer LN1+QKV ----------------
__global__ __launch_bounds__(256) void k_post(
        const float* __restrict__ o, const float* __restrict__ Wo, const float* __restrict__ bo,
        const float* __restrict__ g2, const float* __restrict__ bg2,
        const float* __restrict__ W1, const float* __restrict__ b1,
        const float* __restrict__ W2, const float* __restrict__ b2m,
        float* __restrict__ x,
        const float* __restrict__ g1n, const float* __restrict__ b1n,
        const float* __restrict__ Wqn, const float* __restrict__ Wkn,
        const float* __restrict__ Wvn,
        float* __restrict__ q, float* __restrict__ k, float* __restrict__ v,
        const float* __restrict__ lg, const float* __restrict__ lb,
        __hip_bfloat16* __restrict__ xfb, int last) {
    __shared__ float os[16][65];
    __shared__ float xs[16][65];
    __shared__ float as[16][257];
    int t = threadIdx.x;
    int r0 = blockIdx.x * 16;
    for (int i = t; i < 16 * 64; i += 256)
        os[i >> 6][i & 63] = o[r0 * 64 + i];
    __syncthreads();
    int c = t & 63, rg = t >> 6;
    {
        float pr[4] = {0.f, 0.f, 0.f, 0.f};
        for (int kk = 0; kk < 64; kk++) {
            float w = Wo[kk * 64 + c];
            #pragma unroll
            for (int i = 0; i < 4; i++) pr[i] += os[rg * 4 + i][kk] * w;
        }
        float bias = bo[c];
        #pragma unroll
        for (int i = 0; i < 4; i++) {
            int row = rg * 4 + i;
            xs[row][c] = x[(r0 + row) * 64 + c] + pr[i] + bias;
        }
    }
    __syncthreads();
    {
        int row = t >> 4, sub = t & 15;
        float s = 0.f, s2 = 0.f;
        #pragma unroll
        for (int j = 0; j < 4; j++) { float vv = xs[row][sub * 4 + j]; s += vv; s2 += vv * vv; }
        #pragma unroll
        for (int off = 1; off < 16; off <<= 1) { s += __shfl_xor(s, off); s2 += __shfl_xor(s2, off); }
        float mu = s * (1.f / 64.f);
        float var = s2 * (1.f / 64.f) - mu * mu;
        float rs = rsqrtf(var + EPS);
        #pragma unroll
        for (int j = 0; j < 4; j++) {
            int d = sub * 4 + j;
            os[row][d] = (xs[row][d] - mu) * rs * g2[d] + bg2[d];
        }
    }
    __syncthreads();
    {
        float m1[16];
        #pragma unroll
        for (int i = 0; i < 16; i++) m1[i] = 0.f;
        for (int kk = 0; kk < 64; kk++) {
            float w = W1[kk * NF + t];
            #pragma unroll
            for (int i = 0; i < 16; i++) m1[i] += os[i][kk] * w;
        }
        float bb1 = b1[t];
        #pragma unroll
        for (int i = 0; i < 16; i++) as[i][t] = fmaxf(m1[i] + bb1, 0.f);
    }
    __syncthreads();
    {
        float m2[4] = {0.f, 0.f, 0.f, 0.f};
        for (int kk = 0; kk < 256; kk++) {
            float w = W2[kk * 64 + c];
            #pragma unroll
            for (int i = 0; i < 4; i++) m2[i] += as[rg * 4 + i][kk] * w;
        }
        float bias = b2m[c];
        #pragma unroll
        for (int i = 0; i < 4; i++) {
            int row = rg * 4 + i;
            xs[row][c] += m2[i] + bias;        // new residual x
        }
    }
    __syncthreads();

    if (last) {
        int row = t >> 4, sub = t & 15;
        float s = 0.f, s2 = 0.f;
        #pragma unroll
        for (int j = 0; j < 4; j++) { float vv = xs[row][sub * 4 + j]; s += vv; s2 += vv * vv; }
        #pragma unroll
        for (int off = 1; off < 16; off <<= 1) { s += __shfl_xor(s, off); s2 += __shfl_xor(s2, off); }
        float mu = s * (1.f / 64.f);
        float var = s2 * (1.f / 64.f) - mu * mu;
        float rs = rsqrtf(var + EPS);
        #pragma unroll
        for (int j = 0; j < 4; j++) {
            int d = sub * 4 + j;
            float val = (xs[row][d] - mu) * rs * lg[d] + lb[d];
            xfb[(r0 + row) * 64 + d] = __float2bfloat16(val);
        }
        return;
    }

    {
        #pragma unroll
        for (int i = 0; i < 4; i++) {
            int row = rg * 4 + i;
            x[(r0 + row) * 64 + c] = xs[row][c];
        }
    }
    {
        int row = t >> 4, sub = t & 15;
        float s = 0.f, s2 = 0.f;
        #pragma unroll
        for (int j = 0; j < 4; j++) { float vv = xs[row][sub * 4 + j]; s += vv; s2 += vv * vv; }
        #pragma unroll
        for (int off = 1; off < 16; off <<= 1) { s += __shfl_xor(s, off); s2 += __shfl_xor(s2, off); }
        float mu = s * (1.f / 64.f);
        float var = s2 * (1.f / 64.f) - mu * mu;
        float rs = rsqrtf(var + EPS);
        #pragma unroll
        for (int j = 0; j < 4; j++) {
            int d = sub * 4 + j;
            os[row][d] = (xs[row][d] - mu) * rs * g1n[d] + b1n[d];
        }
    }
    __syncthreads();
    {
        int head = c >> 4, sidx = c & 15;
        float aq[4], ak[4], av[4];
        #pragma unroll
        for (int i = 0; i < 4; i++) { aq[i] = 0.f; ak[i] = 0.f; av[i] = 0.f; }
        for (int kk = 0; kk < 64; kk++) {
            float wq = Wqn[(head * 64 + kk) * 16 + sidx];
            float wk = Wkn[(head * 64 + kk) * 16 + sidx];
            float wv = Wvn[(head * 64 + kk) * 16 + sidx];
            #pragma unroll
            for (int i = 0; i < 4; i++) {
                float h = os[rg * 4 + i][kk];
                aq[i] += h * wq; ak[i] += h * wk; av[i] += h * wv;
            }
        }
        #pragma unroll
        for (int i = 0; i < 4; i++) {
            int n = r0 + rg * 4 + i;
            int b = n >> 8, tt = n & 255;
            int oidx = ((b * NH + head) * NT + tt) * NHS + sidx;
            q[oidx] = aq[i]; k[oidx] = ak[i]; v[oidx] = av[i];
        }
    }
}

// ---------------- Whead [64][NV] f32 -> transposed bf16 [NVP][64] ----------------
__global__ __launch_bounds__(256) void k_convW(
        const float* __restrict__ Wh, __hip_bfloat16* __restrict__ whb) {
    __shared__ float w[64][65];
    int t = threadIdx.x;
    int n0 = blockIdx.x * 64;
    for (int i = t; i < 64 * 64; i += 256) {
        int k = i >> 6, c = i & 63;
        int n = n0 + c;
        w[k][c] = (n < NV) ? Wh[k * NV + n] : 0.f;
    }
    __syncthreads();
    int c = t >> 2, kq = t & 3;
    int n = n0 + c;
    union { __hip_bfloat16 h[16]; uint4 u[2]; } pk;
    #pragma unroll
    for (int j = 0; j < 16; j++)
        pk.h[j] = __float2bfloat16(w[kq * 16 + j][c]);
    uint4* dst = (uint4*)(whb + (size_t)n * 64 + kq * 16);
    dst[0] = pk.u[0];
    dst[1] = pk.u[1];
}

// ---------------- head GEMM: 64 rows x 1024 cols per block ----------------
// grid = 8 XCD x 8 row-panels x 50 steps = 3200 blocks, 4 waves each.
// Row-panel pinned to an XCD; steps sweep in dispatch order => each 201KB
// output row is written as 50 near-sequential 4KB chunks from one XCD, and
// the 128KB whb step-slice is L2-shared by that XCD's 8 co-resident blocks.
// Per-row sum-exp partials land in wsp[step*NN+row] (deterministic).
__global__ __launch_bounds__(256) void k_head(
        const __hip_bfloat16* __restrict__ xfb, const __hip_bfloat16* __restrict__ whb,
        const float* __restrict__ bhead, float* __restrict__ out,
        float* __restrict__ wsp) {
    __shared__ float ssm[4][64];

    int i0 = blockIdx.x;
    int xcd = i0 & 7;
    int j   = i0 >> 3;
    int rbl = j & 7;
    int step = j >> 3;                  // 0..49
    int rb = xcd * 8 + rbl;             // 0..63
    int r0 = rb * 64;

    int t = threadIdx.x;
    int w = t >> 6, l = t & 63;
    int lr = l & 15, lg = l >> 4;
    int cw0 = step * 1024 + w * 256;    // wave's 256-col slab

    // A fragments: a[m][ks], lane holds A[r0+m*16+lr][ks*32+lg*8 ..+7]
    bf16x8 a[4][2];
    {
        const __hip_bfloat16* ap = xfb + (size_t)(r0 + lr) * 64 + lg * 8;
        #pragma unroll
        for (int m = 0; m < 4; m++) {
            a[m][0] = *reinterpret_cast<const bf16x8*>(ap + m * 16 * 64);
            a[m][1] = *reinterpret_cast<const bf16x8*>(ap + m * 16 * 64 + 32);
        }
    }

    float es[16];
    #pragma unroll
    for (int i = 0; i < 16; i++) es[i] = 0.f;

    // 4 column chunks of 64 cols each
    #pragma unroll
    for (int cc = 0; cc < 4; cc++) {
        int gc = cw0 + cc * 64 + lr * 4;        // lane's first col in chunk
        const __hip_bfloat16* bp = whb + (size_t)gc * 64 + lg * 8;
        bf16x8 bfr[4][2];
        #pragma unroll
        for (int n = 0; n < 4; n++) {
            bfr[n][0] = *reinterpret_cast<const bf16x8*>(bp + n * 64);
            bfr[n][1] = *reinterpret_cast<const bf16x8*>(bp + n * 64 + 32);
        }
        f32x4 acc[4][4];
        #pragma unroll
        for (int m = 0; m < 4; m++)
            #pragma unroll
            for (int n = 0; n < 4; n++)
                #pragma unroll
                for (int j2 = 0; j2 < 4; j2++) acc[m][n][j2] = 0.f;
        #pragma unroll
        for (int ks = 0; ks < 2; ks++)
            #pragma unroll
            for (int m = 0; m < 4; m++)
                #pragma unroll
                for (int n = 0; n < 4; n++)
                    acc[m][n] = __builtin_amdgcn_mfma_f32_16x16x32_bf16(a[m][ks], bfr[n][ks], acc[m][n], 0, 0, 0);

        bool all4 = (gc + 3 < NV);
        if (all4) {
            float4 bv = *(const float4*)(bhead + gc);
            float bias[4] = {bv.x, bv.y, bv.z, bv.w};
            #pragma unroll
            for (int m = 0; m < 4; m++) {
                #pragma unroll
                for (int i = 0; i < 4; i++) {
                    int grow = r0 + m * 16 + 4 * lg + i;
                    f32x4 vv;
                    float e = 0.f;
                    #pragma unroll
                    for (int n = 0; n < 4; n++) {
                        float v = acc[m][n][i] + bias[n];
                        vv[n] = v;
                        e += __expf(v);
                    }
                    es[m * 4 + i] += e;
                    __builtin_nontemporal_store(vv, (f32x4*)(out + (size_t)grow * NV + gc));
                }
            }
        } else {
            float bias[4];
            bool cok[4];
            #pragma unroll
            for (int n = 0; n < 4; n++) {
                cok[n] = (gc + n < NV);
                bias[n] = cok[n] ? bhead[gc + n] : 0.f;
            }
            #pragma unroll
            for (int m = 0; m < 4; m++) {
                #pragma unroll
                for (int i = 0; i < 4; i++) {
                    int grow = r0 + m * 16 + 4 * lg + i;
                    float* dst = out + (size_t)grow * NV + gc;
                    float e = 0.f;
                    #pragma unroll
                    for (int n = 0; n < 4; n++) {
                        if (cok[n]) {
                            float v = acc[m][n][i] + bias[n];
                            e += __expf(v);
                            __builtin_nontemporal_store(v, dst + n);
                        }
                    }
                    es[m * 4 + i] += e;
                }
            }
        }
    }

    // reduce es over the 16 lr lanes
    #pragma unroll
    for (int m = 0; m < 4; m++) {
        #pragma unroll
        for (int i = 0; i < 4; i++) {
            float e = es[m * 4 + i];
            #pragma unroll
            for (int off = 1; off < 16; off <<= 1) e += __shfl_xor(e, off);
            if (lr == 0) ssm[w][m * 16 + 4 * lg + i] = e;
        }
    }
    __syncthreads();
    if (t < 64)
        wsp[(size_t)step * NN + r0 + t] = ssm[0][t] + ssm[1][t] + ssm[2][t] + ssm[3][t];
}

// ---------------- loss stage 1: lp[row] = logit[target] - log(sum over steps) ----------------
__global__ void k_loss1(const float* __restrict__ wsp,
                        const float* __restrict__ out, const int* __restrict__ targets,
                        float* __restrict__ lp) {
    int row = blockIdx.x * blockDim.x + threadIdx.x;
    if (row >= NN) return;
    float S = 0.f;
    for (int s = 0; s < NSTEP; s++)
        S += wsp[(size_t)s * NN + row];
    float lse = logf(S);
    int tg = targets[row];
    float lt = out[(size_t)row * NV + tg];
    lp[row] = lt - lse;
}

// ---------------- loss stage 2: deterministic mean ----------------
__global__ void k_loss2(const float* __restrict__ lp, float* __restrict__ out) {
    __shared__ float red[4];
    int t = threadIdx.x;
    float s = 0.f;
    for (int i = t; i < NN; i += 256) s += lp[i];
    for (int off = 1; off < 64; off <<= 1) s += __shfl_xor(s, off);
    if ((t & 63) == 0) red[t >> 6] = s;
    __syncthreads();
    if (t == 0) {
        float tot = red[0] + red[1] + red[2] + red[3];
        out[LOGITS] = -tot / (float)NN;
    }
}

extern "C" void kernel_launch(void* const* d_in, const int* in_sizes, int n_in,
                              void* d_out, int out_size, void* d_ws, size_t ws_size,
                              hipStream_t stream) {
    const int*   idx     = (const int*)d_in[0];
    const int*   targets = (const int*)d_in[1];
    const float* tok     = (const float*)d_in[2];
    const float* pos     = (const float*)d_in[3];
    const float* Wq      = (const float*)d_in[4];
    const float* Wk      = (const float*)d_in[5];
    const float* Wv      = (const float*)d_in[6];
    const float* Wo      = (const float*)d_in[7];
    const float* bo      = (const float*)d_in[8];
    const float* ln1g    = (const float*)d_in[9];
    const float* ln1b    = (const float*)d_in[10];
    const float* ln2g    = (const float*)d_in[11];
    const float* ln2b    = (const float*)d_in[12];
    const float* W1      = (const float*)d_in[13];
    const float* b1      = (const float*)d_in[14];
    const float* W2      = (const float*)d_in[15];
    const float* b2      = (const float*)d_in[16];
    const float* lnfg    = (const float*)d_in[17];
    const float* lnfb    = (const float*)d_in[18];
    const float* Wh      = (const float*)d_in[19];
    const float* bhead   = (const float*)d_in[20];

    float* ws = (float*)d_ws;
    float* x  = ws + X_OFF;
    float* q  = ws + Q_OFF;
    float* k  = ws + K_OFF;
    float* v  = ws + V_OFF;
    float* o  = ws + O_OFF;
    __hip_bfloat16* xfb = (__hip_bfloat16*)(ws + XFB_OFF);
    float* wsp = ws + WS2_OFF;
    __hip_bfloat16* whb = (__hip_bfloat16*)(ws + WHB_OFF);
    float* lp  = ws + LP_OFF;
    float* out = (float*)d_out;

    k_convW<<<NVP / 64, 256, 0, stream>>>(Wh, whb);

    k_ln_qkv<<<NN / 16, 256, 0, stream>>>(x, ln1g, ln1b, Wq, Wk, Wv, q, k, v,
                                          idx, tok, pos);

    for (int l = 0; l < NL; l++) {
        int last = (l == NL - 1) ? 1 : 0;
        int ln = last ? l : l + 1;
        k_attn<<<NB * NH * 4, 256, 0, stream>>>(q, k, v, o);
        k_post<<<NN / 16, 256, 0, stream>>>(o, Wo + l * ND * ND, bo + l * ND,
                                            ln2g + l * ND, ln2b + l * ND,
                                            W1 + l * ND * NF, b1 + l * NF,
                                            W2 + l * NF * ND, b2 + l * ND, x,
                                            ln1g + ln * ND, ln1b + ln * ND,
                                            Wq + ln * NH * ND * NHS,
                                            Wk + ln * NH * ND * NHS,
                                            Wv + ln * NH * ND * NHS,
                                            q, k, v,
                                            lnfg, lnfb, xfb, last);
    }

    k_head<<<8 * 8 * NSTEP, 256, 0, stream>>>(xfb, whb, bhead, out, wsp);

    k_loss1<<<NN / 256, 256, 0, stream>>>(wsp, out, targets, lp);
    k_loss2<<<1, 256, 0, stream>>>(lp, out);
}

// Round 11
// 495.477 us; speedup vs baseline: 1.3443x; 1.3443x over previous
//
#include <hip/hip_runtime.h>
#include <hip/hip_bf16.h>
#include <math.h>

// GPT forward: V=50257, B=16, T=256, D=64, H=4, HS=16, L=4, F=256
constexpr int NV  = 50257;
constexpr int NB  = 16;
constexpr int NT  = 256;
constexpr int ND  = 64;
constexpr int NH  = 4;
constexpr int NHS = 16;
constexpr int NL  = 4;
constexpr int NF  = 256;
constexpr int NN  = NB * NT;        // 4096 rows
constexpr float EPS = 1e-5f;

constexpr int NCB2 = 200;                    // head col blocks of 256 (8-divisible)
constexpr int NVP  = NCB2 * 256;             // 51200 padded vocab
constexpr int LOGITS = NN * NV;              // 205,852,672
constexpr int RB_N  = NN / 64;               // 64 row blocks
constexpr int CB_PER_XCD = NCB2 / 8;         // 25

// workspace layout (float offsets)
constexpr int X_OFF   = 0;                        // [NN*ND] f32
constexpr int Q_OFF   = X_OFF  + NN * ND;         // bf16 [B,H,T,HS]
constexpr int K_OFF   = Q_OFF  + NN * ND;
constexpr int V_OFF   = K_OFF  + NN * ND;
constexpr int O_OFF   = V_OFF  + NN * ND;         // f32 [NN][64]
constexpr int A_OFF   = O_OFF  + NN * ND;         // (spacer)
constexpr int XFB_OFF = A_OFF  + NN * NF;         // bf16 [NN*ND]
constexpr int WM_OFF  = XFB_OFF + NN * ND / 2;    // (spacer)
constexpr int WS2_OFF = WM_OFF + 200 * NN;        // [NCB2*NN] sum-exp partials
constexpr int WHB_OFF = WS2_OFF + 200 * NN;       // bf16 [NVP*64]
constexpr int LP_OFF  = WHB_OFF + NVP * 32;       // [NN]

typedef __bf16 bf16x8 __attribute__((ext_vector_type(8)));
typedef float  f32x4  __attribute__((ext_vector_type(4)));

// ---------------- embed + LN1 + QKV (layer 0 only; 16 rows/block, 256 blocks) ----------------
__global__ __launch_bounds__(256) void k_ln_qkv(
        float* __restrict__ x, const float* __restrict__ g, const float* __restrict__ bb,
        const float* __restrict__ Wq, const float* __restrict__ Wk, const float* __restrict__ Wv,
        __hip_bfloat16* __restrict__ q, __hip_bfloat16* __restrict__ k,
        __hip_bfloat16* __restrict__ v,
        const int* __restrict__ idx, const float* __restrict__ tok,
        const float* __restrict__ pos) {
    __shared__ float hs[16][65];
    int t = threadIdx.x;
    int r0 = blockIdx.x * 16;
    for (int i = t; i < 16 * 64; i += 256) {
        int n = r0 + (i >> 6);
        int tt = n & (NT - 1), d = i & 63;
        float e = tok[idx[n] * ND + d] + pos[tt * ND + d];
        hs[i >> 6][i & 63] = e;
        x[(size_t)r0 * 64 + i] = e;
    }
    __syncthreads();
    {
        int row = t >> 4, sub = t & 15;
        float s = 0.f, s2 = 0.f;
        #pragma unroll
        for (int j = 0; j < 4; j++) { float vv = hs[row][sub * 4 + j]; s += vv; s2 += vv * vv; }
        #pragma unroll
        for (int off = 1; off < 16; off <<= 1) { s += __shfl_xor(s, off); s2 += __shfl_xor(s2, off); }
        float mu = s * (1.f / 64.f);
        float var = s2 * (1.f / 64.f) - mu * mu;
        float rs = rsqrtf(var + EPS);
        #pragma unroll
        for (int j = 0; j < 4; j++) {
            int d = sub * 4 + j;
            hs[row][d] = (hs[row][d] - mu) * rs * g[d] + bb[d];
        }
    }
    __syncthreads();
    int c = t & 63, rg = t >> 6;
    int head = c >> 4, sidx = c & 15;
    float aq[4], ak[4], av[4];
    #pragma unroll
    for (int i = 0; i < 4; i++) { aq[i] = 0.f; ak[i] = 0.f; av[i] = 0.f; }
    for (int kk = 0; kk < 64; kk++) {
        float wq = Wq[(head * 64 + kk) * 16 + sidx];
        float wk = Wk[(head * 64 + kk) * 16 + sidx];
        float wv = Wv[(head * 64 + kk) * 16 + sidx];
        #pragma unroll
        for (int i = 0; i < 4; i++) {
            float h = hs[rg * 4 + i][kk];
            aq[i] += h * wq; ak[i] += h * wk; av[i] += h * wv;
        }
    }
    #pragma unroll
    for (int i = 0; i < 4; i++) {
        int n = r0 + rg * 4 + i;
        int b = n >> 8, tt = n & 255;
        int oidx = ((b * NH + head) * NT + tt) * NHS + sidx;
        q[oidx] = __float2bfloat16(aq[i]);
        k[oidx] = __float2bfloat16(ak[i]);
        v[oidx] = __float2bfloat16(av[i]);
    }
}

// ---------------- MFMA flash attention ----------------
// grid 256 = (bh, tq); 4 waves; wave w owns q-rows qb=tq*64+w*16 .. +15.
// Per 16-key tile: QK^T mfma (hs padded 16->32), exp (no max-sub), P->bf16
// via per-wave LDS, PV mfma (keys padded 16->32). Final O = acc / rowsum.
__global__ __launch_bounds__(256) void k_attn(
        const __hip_bfloat16* __restrict__ q, const __hip_bfloat16* __restrict__ k,
        const __hip_bfloat16* __restrict__ v, float* __restrict__ o) {
    __shared__ __bf16 ks[256][24];     // K rows, padded (48B stride)
    __shared__ __bf16 vt[16][264];     // V transposed [hs][key], padded (528B stride)
    __shared__ __bf16 ps[4][16][40];   // per-wave P [q][key], padded (80B stride)

    int blk = blockIdx.x;
    int bh = blk >> 2, tq = blk & 3;
    int t = threadIdx.x;
    int w = t >> 6, l = t & 63;
    int lr = l & 15, lg = l >> 4;
    int nrows = tq * 64 + 64;

    const __hip_bfloat16* kbp = k + (size_t)bh * NT * NHS;
    const __hip_bfloat16* vbp = v + (size_t)bh * NT * NHS;
    for (int r = t; r < nrows; r += 256) {
        const uint4* src = (const uint4*)(kbp + r * 16);
        uint4 k0 = src[0], k1 = src[1];
        *(uint4*)&ks[r][0] = k0;
        *(uint4*)&ks[r][8] = k1;
        const uint4* vsrc = (const uint4*)(vbp + r * 16);
        union { uint4 u[2]; __bf16 h[16]; } vu;
        vu.u[0] = vsrc[0]; vu.u[1] = vsrc[1];
        #pragma unroll
        for (int hh = 0; hh < 16; hh++)
            vt[hh][r] = vu.h[hh];
    }
    __syncthreads();

    bf16x8 zero8;
    #pragma unroll
    for (int e = 0; e < 8; e++) zero8[e] = (__bf16)0.0f;

    int qb = tq * 64 + w * 16;
    bf16x8 qf = zero8;
    if (lg < 2)
        qf = *reinterpret_cast<const bf16x8*>(q + ((size_t)bh * NT + qb + lr) * 16 + lg * 8);

    int ntiles = tq * 4 + w + 1;
    f32x4 oacc = {0.f, 0.f, 0.f, 0.f};
    float lsum[4] = {0.f, 0.f, 0.f, 0.f};

    for (int kt = 0; kt < ntiles; kt++) {
        int kb2 = kt * 16;
        bool diag = (kt == ntiles - 1);

        bf16x8 kf = zero8;
        if (lg < 2)
            kf = *reinterpret_cast<const bf16x8*>(&ks[kb2 + lr][lg * 8]);

        f32x4 s4 = {0.f, 0.f, 0.f, 0.f};
        s4 = __builtin_amdgcn_mfma_f32_16x16x32_bf16(qf, kf, s4, 0, 0, 0);
        // S[row=lg*4+reg (q)][col=lr (key)]

        #pragma unroll
        for (int reg = 0; reg < 4; reg++) {
            float pv = __expf(s4[reg]);
            if (diag && lr > lg * 4 + reg) pv = 0.f;
            lsum[reg] += pv;
            ps[w][lg * 4 + reg][lr] = (__bf16)pv;
        }

        bf16x8 pf = zero8, vf = zero8;
        if (lg < 2) {
            pf = *reinterpret_cast<const bf16x8*>(&ps[w][lr][lg * 8]);
            vf = *reinterpret_cast<const bf16x8*>(&vt[lr][kb2 + lg * 8]);
        }
        oacc = __builtin_amdgcn_mfma_f32_16x16x32_bf16(pf, vf, oacc, 0, 0, 0);
        // O[row=lg*4+reg (q)][col=lr (hs)]
    }

    #pragma unroll
    for (int reg = 0; reg < 4; reg++) {
        float e = lsum[reg];
        #pragma unroll
        for (int off = 1; off < 16; off <<= 1) e += __shfl_xor(e, off);
        lsum[reg] = e;
    }

    int b = bh >> 2, h = bh & 3;
    #pragma unroll
    for (int reg = 0; reg < 4; reg++) {
        int qrow = qb + lg * 4 + reg;
        o[((size_t)b * NT + qrow) * ND + h * NHS + lr] = oacc[reg] / lsum[reg];
    }
}

// ---------------- proj+res+LN2+MLP1+MLP2+res, then NEXT-layer LN1+QKV ----------------
__global__ __launch_bounds__(256) void k_post(
        const float* __restrict__ o, const float* __restrict__ Wo, const float* __restrict__ bo,
        const float* __restrict__ g2, const float* __restrict__ bg2,
        const float* __restrict__ W1, const float* __restrict__ b1,
        const float* __restrict__ W2, const float* __restrict__ b2m,
        float* __restrict__ x,
        const float* __restrict__ g1n, const float* __restrict__ b1n,
        const float* __restrict__ Wqn, const float* __restrict__ Wkn,
        const float* __restrict__ Wvn,
        __hip_bfloat16* __restrict__ q, __hip_bfloat16* __restrict__ k,
        __hip_bfloat16* __restrict__ v,
        const float* __restrict__ lg, const float* __restrict__ lb,
        __hip_bfloat16* __restrict__ xfb, int last) {
    __shared__ float os[16][65];
    __shared__ float xs[16][65];
    __shared__ float as[16][257];
    int t = threadIdx.x;
    int r0 = blockIdx.x * 16;
    for (int i = t; i < 16 * 64; i += 256)
        os[i >> 6][i & 63] = o[r0 * 64 + i];
    __syncthreads();
    int c = t & 63, rg = t >> 6;
    {
        float pr[4] = {0.f, 0.f, 0.f, 0.f};
        for (int kk = 0; kk < 64; kk++) {
            float w = Wo[kk * 64 + c];
            #pragma unroll
            for (int i = 0; i < 4; i++) pr[i] += os[rg * 4 + i][kk] * w;
        }
        float bias = bo[c];
        #pragma unroll
        for (int i = 0; i < 4; i++) {
            int row = rg * 4 + i;
            xs[row][c] = x[(r0 + row) * 64 + c] + pr[i] + bias;
        }
    }
    __syncthreads();
    {
        int row = t >> 4, sub = t & 15;
        float s = 0.f, s2 = 0.f;
        #pragma unroll
        for (int j = 0; j < 4; j++) { float vv = xs[row][sub * 4 + j]; s += vv; s2 += vv * vv; }
        #pragma unroll
        for (int off = 1; off < 16; off <<= 1) { s += __shfl_xor(s, off); s2 += __shfl_xor(s2, off); }
        float mu = s * (1.f / 64.f);
        float var = s2 * (1.f / 64.f) - mu * mu;
        float rs = rsqrtf(var + EPS);
        #pragma unroll
        for (int j = 0; j < 4; j++) {
            int d = sub * 4 + j;
            os[row][d] = (xs[row][d] - mu) * rs * g2[d] + bg2[d];
        }
    }
    __syncthreads();
    {
        float m1[16];
        #pragma unroll
        for (int i = 0; i < 16; i++) m1[i] = 0.f;
        for (int kk = 0; kk < 64; kk++) {
            float w = W1[kk * NF + t];
            #pragma unroll
            for (int i = 0; i < 16; i++) m1[i] += os[i][kk] * w;
        }
        float bb1 = b1[t];
        #pragma unroll
        for (int i = 0; i < 16; i++) as[i][t] = fmaxf(m1[i] + bb1, 0.f);
    }
    __syncthreads();
    {
        float m2[4] = {0.f, 0.f, 0.f, 0.f};
        for (int kk = 0; kk < 256; kk++) {
            float w = W2[kk * 64 + c];
            #pragma unroll
            for (int i = 0; i < 4; i++) m2[i] += as[rg * 4 + i][kk] * w;
        }
        float bias = b2m[c];
        #pragma unroll
        for (int i = 0; i < 4; i++) {
            int row = rg * 4 + i;
            xs[row][c] += m2[i] + bias;        // new residual x
        }
    }
    __syncthreads();

    if (last) {
        int row = t >> 4, sub = t & 15;
        float s = 0.f, s2 = 0.f;
        #pragma unroll
        for (int j = 0; j < 4; j++) { float vv = xs[row][sub * 4 + j]; s += vv; s2 += vv * vv; }
        #pragma unroll
        for (int off = 1; off < 16; off <<= 1) { s += __shfl_xor(s, off); s2 += __shfl_xor(s2, off); }
        float mu = s * (1.f / 64.f);
        float var = s2 * (1.f / 64.f) - mu * mu;
        float rs = rsqrtf(var + EPS);
        #pragma unroll
        for (int j = 0; j < 4; j++) {
            int d = sub * 4 + j;
            float val = (xs[row][d] - mu) * rs * lg[d] + lb[d];
            xfb[(r0 + row) * 64 + d] = __float2bfloat16(val);
        }
        return;
    }

    {
        #pragma unroll
        for (int i = 0; i < 4; i++) {
            int row = rg * 4 + i;
            x[(r0 + row) * 64 + c] = xs[row][c];
        }
    }
    {
        int row = t >> 4, sub = t & 15;
        float s = 0.f, s2 = 0.f;
        #pragma unroll
        for (int j = 0; j < 4; j++) { float vv = xs[row][sub * 4 + j]; s += vv; s2 += vv * vv; }
        #pragma unroll
        for (int off = 1; off < 16; off <<= 1) { s += __shfl_xor(s, off); s2 += __shfl_xor(s2, off); }
        float mu = s * (1.f / 64.f);
        float var = s2 * (1.f / 64.f) - mu * mu;
        float rs = rsqrtf(var + EPS);
        #pragma unroll
        for (int j = 0; j < 4; j++) {
            int d = sub * 4 + j;
            os[row][d] = (xs[row][d] - mu) * rs * g1n[d] + b1n[d];
        }
    }
    __syncthreads();
    {
        int head = c >> 4, sidx = c & 15;
        float aq[4], ak[4], av[4];
        #pragma unroll
        for (int i = 0; i < 4; i++) { aq[i] = 0.f; ak[i] = 0.f; av[i] = 0.f; }
        for (int kk = 0; kk < 64; kk++) {
            float wq = Wqn[(head * 64 + kk) * 16 + sidx];
            float wk = Wkn[(head * 64 + kk) * 16 + sidx];
            float wv = Wvn[(head * 64 + kk) * 16 + sidx];
            #pragma unroll
            for (int i = 0; i < 4; i++) {
                float h = os[rg * 4 + i][kk];
                aq[i] += h * wq; ak[i] += h * wk; av[i] += h * wv;
            }
        }
        #pragma unroll
        for (int i = 0; i < 4; i++) {
            int n = r0 + rg * 4 + i;
            int b = n >> 8, tt = n & 255;
            int oidx = ((b * NH + head) * NT + tt) * NHS + sidx;
            q[oidx] = __float2bfloat16(aq[i]);
            k[oidx] = __float2bfloat16(ak[i]);
            v[oidx] = __float2bfloat16(av[i]);
        }
    }
}

// ---------------- Whead [64][NV] f32 -> transposed bf16 [NVP][64] ----------------
__global__ __launch_bounds__(256) void k_convW(
        const float* __restrict__ Wh, __hip_bfloat16* __restrict__ whb) {
    __shared__ float w[64][65];
    int t = threadIdx.x;
    int n0 = blockIdx.x * 64;
    for (int i = t; i < 64 * 64; i += 256) {
        int k = i >> 6, c = i & 63;
        int n = n0 + c;
        w[k][c] = (n < NV) ? Wh[k * NV + n] : 0.f;
    }
    __syncthreads();
    int c = t >> 2, kq = t & 3;
    int n = n0 + c;
    union { __hip_bfloat16 h[16]; uint4 u[2]; } pk;
    #pragma unroll
    for (int j = 0; j < 16; j++)
        pk.h[j] = __float2bfloat16(w[kq * 16 + j][c]);
    uint4* dst = (uint4*)(whb + (size_t)n * 64 + kq * 16);
    dst[0] = pk.u[0];
    dst[1] = pk.u[1];
}

// ---------------- head GEMM (bf16 MFMA) + bias + fused row sum-exp (R8 best) ----------------
__global__ __launch_bounds__(256) void k_head(
        const __hip_bfloat16* __restrict__ xfb, const __hip_bfloat16* __restrict__ whb,
        const float* __restrict__ bhead, float* __restrict__ out,
        float* __restrict__ wsum) {
    __shared__ float ssm[4][64];

    int i0 = blockIdx.x;
    int xcd = i0 & 7;
    int j  = i0 >> 3;
    int rb = j / CB_PER_XCD;
    int cb = xcd * CB_PER_XCD + (j - rb * CB_PER_XCD);

    int t = threadIdx.x;
    int w = t >> 6, l = t & 63;
    int lr = l & 15, lg = l >> 4;
    int r0 = rb * 64;
    int cw = cb * 256 + w * 64;
    int c4 = cw + lr * 4;

    bf16x8 a[4][2], b[4][2];
    {
        const __hip_bfloat16* ap = xfb + (size_t)(r0 + lr) * 64 + lg * 8;
        #pragma unroll
        for (int m = 0; m < 4; m++)
            #pragma unroll
            for (int ks = 0; ks < 2; ks++)
                a[m][ks] = *reinterpret_cast<const bf16x8*>(ap + m * 16 * 64 + ks * 32);
        const __hip_bfloat16* bp = whb + (size_t)c4 * 64 + lg * 8;
        #pragma unroll
        for (int n = 0; n < 4; n++)
            #pragma unroll
            for (int ks = 0; ks < 2; ks++)
                b[n][ks] = *reinterpret_cast<const bf16x8*>(bp + n * 64 + ks * 32);
    }

    f32x4 acc[4][4];
    #pragma unroll
    for (int m = 0; m < 4; m++)
        #pragma unroll
        for (int n = 0; n < 4; n++)
            #pragma unroll
            for (int j2 = 0; j2 < 4; j2++) acc[m][n][j2] = 0.f;

    #pragma unroll
    for (int ks = 0; ks < 2; ks++)
        #pragma unroll
        for (int m = 0; m < 4; m++)
            #pragma unroll
            for (int n = 0; n < 4; n++)
                acc[m][n] = __builtin_amdgcn_mfma_f32_16x16x32_bf16(a[m][ks], b[n][ks], acc[m][n], 0, 0, 0);

    bool all4 = (c4 + 3 < NV);
    float bias[4];
    bool  cok[4];
    if (all4) {
        float4 bv = *(const float4*)(bhead + c4);
        bias[0] = bv.x; bias[1] = bv.y; bias[2] = bv.z; bias[3] = bv.w;
        cok[0] = cok[1] = cok[2] = cok[3] = true;
    } else {
        #pragma unroll
        for (int n = 0; n < 4; n++) {
            int gc = c4 + n;
            cok[n] = (gc < NV);
            bias[n] = cok[n] ? bhead[gc] : 0.f;
        }
    }

    float es[16];
    #pragma unroll
    for (int m = 0; m < 4; m++) {
        #pragma unroll
        for (int i = 0; i < 4; i++) {
            int rl = 4 * lg + i;
            int grow = r0 + m * 16 + rl;
            float vals[4];
            float e = 0.f;
            #pragma unroll
            for (int n = 0; n < 4; n++) {
                float v = acc[m][n][i] + bias[n];
                vals[n] = v;
                if (cok[n]) e += __expf(v);
            }
            es[m * 4 + i] = e;
            float* dst = out + (size_t)grow * NV + c4;
            if (all4) {
                f32x4 vv = {vals[0], vals[1], vals[2], vals[3]};
                __builtin_nontemporal_store(vv, (f32x4*)dst);
            } else {
                #pragma unroll
                for (int n = 0; n < 4; n++)
                    if (cok[n]) __builtin_nontemporal_store(vals[n], dst + n);
            }
        }
    }

    #pragma unroll
    for (int m = 0; m < 4; m++) {
        #pragma unroll
        for (int i = 0; i < 4; i++) {
            float e = es[m * 4 + i];
            #pragma unroll
            for (int off = 1; off < 16; off <<= 1) e += __shfl_xor(e, off);
            if (lr == 0) ssm[w][m * 16 + 4 * lg + i] = e;
        }
    }

    __syncthreads();
    if (t < 64)
        wsum[cb * NN + r0 + t] = ssm[0][t] + ssm[1][t] + ssm[2][t] + ssm[3][t];
}

// ---------------- loss stage 1 ----------------
__global__ void k_loss1(const float* __restrict__ wsum,
                        const float* __restrict__ out, const int* __restrict__ targets,
                        float* __restrict__ lp) {
    int row = blockIdx.x * blockDim.x + threadIdx.x;
    if (row >= NN) return;
    float S = 0.f;
    for (int cb = 0; cb < NCB2; cb++)
        S += wsum[cb * NN + row];
    float lse = logf(S);
    int tg = targets[row];
    float lt = out[(size_t)row * NV + tg];
    lp[row] = lt - lse;
}

// ---------------- loss stage 2 ----------------
__global__ void k_loss2(const float* __restrict__ lp, float* __restrict__ out) {
    __shared__ float red[4];
    int t = threadIdx.x;
    float s = 0.f;
    for (int i = t; i < NN; i += 256) s += lp[i];
    for (int off = 1; off < 64; off <<= 1) s += __shfl_xor(s, off);
    if ((t & 63) == 0) red[t >> 6] = s;
    __syncthreads();
    if (t == 0) {
        float tot = red[0] + red[1] + red[2] + red[3];
        out[LOGITS] = -tot / (float)NN;
    }
}

extern "C" void kernel_launch(void* const* d_in, const int* in_sizes, int n_in,
                              void* d_out, int out_size, void* d_ws, size_t ws_size,
                              hipStream_t stream) {
    const int*   idx     = (const int*)d_in[0];
    const int*   targets = (const int*)d_in[1];
    const float* tok     = (const float*)d_in[2];
    const float* pos     = (const float*)d_in[3];
    const float* Wq      = (const float*)d_in[4];
    const float* Wk      = (const float*)d_in[5];
    const float* Wv      = (const float*)d_in[6];
    const float* Wo      = (const float*)d_in[7];
    const float* bo      = (const float*)d_in[8];
    const float* ln1g    = (const float*)d_in[9];
    const float* ln1b    = (const float*)d_in[10];
    const float* ln2g    = (const float*)d_in[11];
    const float* ln2b    = (const float*)d_in[12];
    const float* W1      = (const float*)d_in[13];
    const float* b1      = (const float*)d_in[14];
    const float* W2      = (const float*)d_in[15];
    const float* b2      = (const float*)d_in[16];
    const float* lnfg    = (const float*)d_in[17];
    const float* lnfb    = (const float*)d_in[18];
    const float* Wh      = (const float*)d_in[19];
    const float* bhead   = (const float*)d_in[20];

    float* ws = (float*)d_ws;
    float* x  = ws + X_OFF;
    __hip_bfloat16* q = (__hip_bfloat16*)(ws + Q_OFF);
    __hip_bfloat16* k = (__hip_bfloat16*)(ws + K_OFF);
    __hip_bfloat16* v = (__hip_bfloat16*)(ws + V_OFF);
    float* o  = ws + O_OFF;
    __hip_bfloat16* xfb = (__hip_bfloat16*)(ws + XFB_OFF);
    float* wsm = ws + WS2_OFF;
    __hip_bfloat16* whb = (__hip_bfloat16*)(ws + WHB_OFF);
    float* lp  = ws + LP_OFF;
    float* out = (float*)d_out;

    k_convW<<<NVP / 64, 256, 0, stream>>>(Wh, whb);

    k_ln_qkv<<<NN / 16, 256, 0, stream>>>(x, ln1g, ln1b, Wq, Wk, Wv, q, k, v,
                                          idx, tok, pos);

    for (int l = 0; l < NL; l++) {
        int last = (l == NL - 1) ? 1 : 0;
        int ln = last ? l : l + 1;
        k_attn<<<NB * NH * 4, 256, 0, stream>>>(q, k, v, o);
        k_post<<<NN / 16, 256, 0, stream>>>(o, Wo + l * ND * ND, bo + l * ND,
                                            ln2g + l * ND, ln2b + l * ND,
                                            W1 + l * ND * NF, b1 + l * NF,
                                            W2 + l * NF * ND, b2 + l * ND, x,
                                            ln1g + ln * ND, ln1b + ln * ND,
                                            Wq + ln * NH * ND * NHS,
                                            Wk + ln * NH * ND * NHS,
                                            Wv + ln * NH * ND * NHS,
                                            q, k, v,
                                            lnfg, lnfb, xfb, last);
    }

    k_head<<<NCB2 * RB_N, 256, 0, stream>>>(xfb, whb, bhead, out, wsm);

    k_loss1<<<NN / 256, 256, 0, stream>>>(wsm, out, targets, lp);
    k_loss2<<<1, 256, 0, stream>>>(lp, out);
}

// Round 12
// 481.359 us; speedup vs baseline: 1.3837x; 1.0293x over previous
//
#include <hip/hip_runtime.h>
#include <hip/hip_bf16.h>
#include <math.h>

// GPT forward: V=50257, B=16, T=256, D=64, H=4, HS=16, L=4, F=256
constexpr int NV  = 50257;
constexpr int NB  = 16;
constexpr int NT  = 256;
constexpr int ND  = 64;
constexpr int NH  = 4;
constexpr int NHS = 16;
constexpr int NL  = 4;
constexpr int NF  = 256;
constexpr int NN  = NB * NT;        // 4096 rows
constexpr float EPS = 1e-5f;

constexpr int NCB2 = 200;                    // head col blocks of 256 (8-divisible)
constexpr int NVP  = NCB2 * 256;             // 51200 padded vocab
constexpr int LOGITS = NN * NV;              // 205,852,672
constexpr int RB_N  = NN / 64;               // 64 row blocks
constexpr int CB_PER_XCD = NCB2 / 8;         // 25

// workspace layout (float offsets)
constexpr int X_OFF   = 0;                        // [NN*ND] f32
constexpr int Q_OFF   = X_OFF  + NN * ND;         // bf16 [B,H,T,HS]
constexpr int K_OFF   = Q_OFF  + NN * ND;
constexpr int V_OFF   = K_OFF  + NN * ND;
constexpr int O_OFF   = V_OFF  + NN * ND;         // f32 [NN][64]
constexpr int A_OFF   = O_OFF  + NN * ND;         // (spacer)
constexpr int XFB_OFF = A_OFF  + NN * NF;         // bf16 [NN*ND]
constexpr int WM_OFF  = XFB_OFF + NN * ND / 2;    // (spacer)
constexpr int WS2_OFF = WM_OFF + 200 * NN;        // [NCB2*NN] sum-exp partials
constexpr int WHB_OFF = WS2_OFF + 200 * NN;       // bf16 [NVP*64]
constexpr int LP_OFF  = WHB_OFF + NVP * 32;       // [NN]

typedef __bf16 bf16x8 __attribute__((ext_vector_type(8)));
typedef float  f32x4  __attribute__((ext_vector_type(4)));

// ---------------- embed + LN1 + QKV (layer 0 only; 16 rows/block, 256 blocks) ----------------
__global__ __launch_bounds__(256) void k_ln_qkv(
        float* __restrict__ x, const float* __restrict__ g, const float* __restrict__ bb,
        const float* __restrict__ Wq, const float* __restrict__ Wk, const float* __restrict__ Wv,
        __hip_bfloat16* __restrict__ q, __hip_bfloat16* __restrict__ k,
        __hip_bfloat16* __restrict__ v,
        const int* __restrict__ idx, const float* __restrict__ tok,
        const float* __restrict__ pos) {
    __shared__ float hs[16][65];
    int t = threadIdx.x;
    int r0 = blockIdx.x * 16;
    for (int i = t; i < 16 * 64; i += 256) {
        int n = r0 + (i >> 6);
        int tt = n & (NT - 1), d = i & 63;
        float e = tok[idx[n] * ND + d] + pos[tt * ND + d];
        hs[i >> 6][i & 63] = e;
        x[(size_t)r0 * 64 + i] = e;
    }
    __syncthreads();
    {
        int row = t >> 4, sub = t & 15;
        float s = 0.f, s2 = 0.f;
        #pragma unroll
        for (int j = 0; j < 4; j++) { float vv = hs[row][sub * 4 + j]; s += vv; s2 += vv * vv; }
        #pragma unroll
        for (int off = 1; off < 16; off <<= 1) { s += __shfl_xor(s, off); s2 += __shfl_xor(s2, off); }
        float mu = s * (1.f / 64.f);
        float var = s2 * (1.f / 64.f) - mu * mu;
        float rs = rsqrtf(var + EPS);
        #pragma unroll
        for (int j = 0; j < 4; j++) {
            int d = sub * 4 + j;
            hs[row][d] = (hs[row][d] - mu) * rs * g[d] + bb[d];
        }
    }
    __syncthreads();
    int c = t & 63, rg = t >> 6;
    int head = c >> 4, sidx = c & 15;
    float aq[4], ak[4], av[4];
    #pragma unroll
    for (int i = 0; i < 4; i++) { aq[i] = 0.f; ak[i] = 0.f; av[i] = 0.f; }
    for (int kk = 0; kk < 64; kk++) {
        float wq = Wq[(head * 64 + kk) * 16 + sidx];
        float wk = Wk[(head * 64 + kk) * 16 + sidx];
        float wv = Wv[(head * 64 + kk) * 16 + sidx];
        #pragma unroll
        for (int i = 0; i < 4; i++) {
            float h = hs[rg * 4 + i][kk];
            aq[i] += h * wq; ak[i] += h * wk; av[i] += h * wv;
        }
    }
    #pragma unroll
    for (int i = 0; i < 4; i++) {
        int n = r0 + rg * 4 + i;
        int b = n >> 8, tt = n & 255;
        int oidx = ((b * NH + head) * NT + tt) * NHS + sidx;
        q[oidx] = __float2bfloat16(aq[i]);
        k[oidx] = __float2bfloat16(ak[i]);
        v[oidx] = __float2bfloat16(av[i]);
    }
}

// ---------------- MFMA flash attention (unchanged from R11) ----------------
__global__ __launch_bounds__(256) void k_attn(
        const __hip_bfloat16* __restrict__ q, const __hip_bfloat16* __restrict__ k,
        const __hip_bfloat16* __restrict__ v, float* __restrict__ o) {
    __shared__ __bf16 ks[256][24];
    __shared__ __bf16 vt[16][264];
    __shared__ __bf16 ps[4][16][40];

    int blk = blockIdx.x;
    int bh = blk >> 2, tq = blk & 3;
    int t = threadIdx.x;
    int w = t >> 6, l = t & 63;
    int lr = l & 15, lg = l >> 4;
    int nrows = tq * 64 + 64;

    const __hip_bfloat16* kbp = k + (size_t)bh * NT * NHS;
    const __hip_bfloat16* vbp = v + (size_t)bh * NT * NHS;
    for (int r = t; r < nrows; r += 256) {
        const uint4* src = (const uint4*)(kbp + r * 16);
        uint4 k0 = src[0], k1 = src[1];
        *(uint4*)&ks[r][0] = k0;
        *(uint4*)&ks[r][8] = k1;
        const uint4* vsrc = (const uint4*)(vbp + r * 16);
        union { uint4 u[2]; __bf16 h[16]; } vu;
        vu.u[0] = vsrc[0]; vu.u[1] = vsrc[1];
        #pragma unroll
        for (int hh = 0; hh < 16; hh++)
            vt[hh][r] = vu.h[hh];
    }
    __syncthreads();

    bf16x8 zero8;
    #pragma unroll
    for (int e = 0; e < 8; e++) zero8[e] = (__bf16)0.0f;

    int qb = tq * 64 + w * 16;
    bf16x8 qf = zero8;
    if (lg < 2)
        qf = *reinterpret_cast<const bf16x8*>(q + ((size_t)bh * NT + qb + lr) * 16 + lg * 8);

    int ntiles = tq * 4 + w + 1;
    f32x4 oacc = {0.f, 0.f, 0.f, 0.f};
    float lsum[4] = {0.f, 0.f, 0.f, 0.f};

    for (int kt = 0; kt < ntiles; kt++) {
        int kb2 = kt * 16;
        bool diag = (kt == ntiles - 1);

        bf16x8 kf = zero8;
        if (lg < 2)
            kf = *reinterpret_cast<const bf16x8*>(&ks[kb2 + lr][lg * 8]);

        f32x4 s4 = {0.f, 0.f, 0.f, 0.f};
        s4 = __builtin_amdgcn_mfma_f32_16x16x32_bf16(qf, kf, s4, 0, 0, 0);

        #pragma unroll
        for (int reg = 0; reg < 4; reg++) {
            float pv = __expf(s4[reg]);
            if (diag && lr > lg * 4 + reg) pv = 0.f;
            lsum[reg] += pv;
            ps[w][lg * 4 + reg][lr] = (__bf16)pv;
        }

        bf16x8 pf = zero8, vf = zero8;
        if (lg < 2) {
            pf = *reinterpret_cast<const bf16x8*>(&ps[w][lr][lg * 8]);
            vf = *reinterpret_cast<const bf16x8*>(&vt[lr][kb2 + lg * 8]);
        }
        oacc = __builtin_amdgcn_mfma_f32_16x16x32_bf16(pf, vf, oacc, 0, 0, 0);
    }

    #pragma unroll
    for (int reg = 0; reg < 4; reg++) {
        float e = lsum[reg];
        #pragma unroll
        for (int off = 1; off < 16; off <<= 1) e += __shfl_xor(e, off);
        lsum[reg] = e;
    }

    int b = bh >> 2, h = bh & 3;
    #pragma unroll
    for (int reg = 0; reg < 4; reg++) {
        int qrow = qb + lg * 4 + reg;
        o[((size_t)b * NT + qrow) * ND + h * NHS + lr] = oacc[reg] / lsum[reg];
    }
}

// ---------------- proj+res+LN2+MLP1+MLP2+res + next LN1/QKV: 8 rows/block, 512 blocks ----------------
__global__ __launch_bounds__(256) void k_post(
        const float* __restrict__ o, const float* __restrict__ Wo, const float* __restrict__ bo,
        const float* __restrict__ g2, const float* __restrict__ bg2,
        const float* __restrict__ W1, const float* __restrict__ b1,
        const float* __restrict__ W2, const float* __restrict__ b2m,
        float* __restrict__ x,
        const float* __restrict__ g1n, const float* __restrict__ b1n,
        const float* __restrict__ Wqn, const float* __restrict__ Wkn,
        const float* __restrict__ Wvn,
        __hip_bfloat16* __restrict__ q, __hip_bfloat16* __restrict__ k,
        __hip_bfloat16* __restrict__ v,
        const float* __restrict__ lg, const float* __restrict__ lb,
        __hip_bfloat16* __restrict__ xfb, int last) {
    __shared__ float os[8][65];
    __shared__ float xs[8][65];
    __shared__ float as[8][257];
    int t = threadIdx.x;
    int r0 = blockIdx.x * 8;
    for (int i = t; i < 8 * 64; i += 256)
        os[i >> 6][i & 63] = o[r0 * 64 + i];
    __syncthreads();
    int c = t & 63, rg = t >> 6;          // rg = wave, owns rows rg*2, rg*2+1
    {
        float pr[2] = {0.f, 0.f};
        for (int kk = 0; kk < 64; kk++) {
            float w = Wo[kk * 64 + c];
            #pragma unroll
            for (int i = 0; i < 2; i++) pr[i] += os[rg * 2 + i][kk] * w;
        }
        float bias = bo[c];
        #pragma unroll
        for (int i = 0; i < 2; i++) {
            int row = rg * 2 + i;
            xs[row][c] = x[(r0 + row) * 64 + c] + pr[i] + bias;
        }
    }
    __syncthreads();
    {
        int row = t >> 5, sub = t & 31;   // 8 rows x 32 threads, 2 elems each
        float s = 0.f, s2 = 0.f;
        #pragma unroll
        for (int j = 0; j < 2; j++) { float vv = xs[row][sub * 2 + j]; s += vv; s2 += vv * vv; }
        #pragma unroll
        for (int off = 1; off < 32; off <<= 1) { s += __shfl_xor(s, off); s2 += __shfl_xor(s2, off); }
        float mu = s * (1.f / 64.f);
        float var = s2 * (1.f / 64.f) - mu * mu;
        float rs = rsqrtf(var + EPS);
        #pragma unroll
        for (int j = 0; j < 2; j++) {
            int d = sub * 2 + j;
            os[row][d] = (xs[row][d] - mu) * rs * g2[d] + bg2[d];
        }
    }
    __syncthreads();
    {
        float m1[8];
        #pragma unroll
        for (int i = 0; i < 8; i++) m1[i] = 0.f;
        for (int kk = 0; kk < 64; kk++) {
            float w = W1[kk * NF + t];
            #pragma unroll
            for (int i = 0; i < 8; i++) m1[i] += os[i][kk] * w;
        }
        float bb1 = b1[t];
        #pragma unroll
        for (int i = 0; i < 8; i++) as[i][t] = fmaxf(m1[i] + bb1, 0.f);
    }
    __syncthreads();
    {
        float m2[2] = {0.f, 0.f};
        for (int kk = 0; kk < 256; kk++) {
            float w = W2[kk * 64 + c];
            #pragma unroll
            for (int i = 0; i < 2; i++) m2[i] += as[rg * 2 + i][kk] * w;
        }
        float bias = b2m[c];
        #pragma unroll
        for (int i = 0; i < 2; i++) {
            int row = rg * 2 + i;
            xs[row][c] += m2[i] + bias;        // new residual x
        }
    }
    __syncthreads();

    if (last) {
        int row = t >> 5, sub = t & 31;
        float s = 0.f, s2 = 0.f;
        #pragma unroll
        for (int j = 0; j < 2; j++) { float vv = xs[row][sub * 2 + j]; s += vv; s2 += vv * vv; }
        #pragma unroll
        for (int off = 1; off < 32; off <<= 1) { s += __shfl_xor(s, off); s2 += __shfl_xor(s2, off); }
        float mu = s * (1.f / 64.f);
        float var = s2 * (1.f / 64.f) - mu * mu;
        float rs = rsqrtf(var + EPS);
        #pragma unroll
        for (int j = 0; j < 2; j++) {
            int d = sub * 2 + j;
            float val = (xs[row][d] - mu) * rs * lg[d] + lb[d];
            xfb[(r0 + row) * 64 + d] = __float2bfloat16(val);
        }
        return;
    }

    {
        #pragma unroll
        for (int i = 0; i < 2; i++) {
            int row = rg * 2 + i;
            x[(r0 + row) * 64 + c] = xs[row][c];
        }
    }
    {
        int row = t >> 5, sub = t & 31;
        float s = 0.f, s2 = 0.f;
        #pragma unroll
        for (int j = 0; j < 2; j++) { float vv = xs[row][sub * 2 + j]; s += vv; s2 += vv * vv; }
        #pragma unroll
        for (int off = 1; off < 32; off <<= 1) { s += __shfl_xor(s, off); s2 += __shfl_xor(s2, off); }
        float mu = s * (1.f / 64.f);
        float var = s2 * (1.f / 64.f) - mu * mu;
        float rs = rsqrtf(var + EPS);
        #pragma unroll
        for (int j = 0; j < 2; j++) {
            int d = sub * 2 + j;
            os[row][d] = (xs[row][d] - mu) * rs * g1n[d] + b1n[d];
        }
    }
    __syncthreads();
    {
        int head = c >> 4, sidx = c & 15;
        float aq[2], ak[2], av[2];
        #pragma unroll
        for (int i = 0; i < 2; i++) { aq[i] = 0.f; ak[i] = 0.f; av[i] = 0.f; }
        for (int kk = 0; kk < 64; kk++) {
            float wq = Wqn[(head * 64 + kk) * 16 + sidx];
            float wk = Wkn[(head * 64 + kk) * 16 + sidx];
            float wv = Wvn[(head * 64 + kk) * 16 + sidx];
            #pragma unroll
            for (int i = 0; i < 2; i++) {
                float h = os[rg * 2 + i][kk];
                aq[i] += h * wq; ak[i] += h * wk; av[i] += h * wv;
            }
        }
        #pragma unroll
        for (int i = 0; i < 2; i++) {
            int n = r0 + rg * 2 + i;
            int b = n >> 8, tt = n & 255;
            int oidx = ((b * NH + head) * NT + tt) * NHS + sidx;
            q[oidx] = __float2bfloat16(aq[i]);
            k[oidx] = __float2bfloat16(ak[i]);
            v[oidx] = __float2bfloat16(av[i]);
        }
    }
}

// ---------------- Whead [64][NV] f32 -> transposed bf16 [NVP][64] ----------------
__global__ __launch_bounds__(256) void k_convW(
        const float* __restrict__ Wh, __hip_bfloat16* __restrict__ whb) {
    __shared__ float w[64][65];
    int t = threadIdx.x;
    int n0 = blockIdx.x * 64;
    for (int i = t; i < 64 * 64; i += 256) {
        int k = i >> 6, c = i & 63;
        int n = n0 + c;
        w[k][c] = (n < NV) ? Wh[k * NV + n] : 0.f;
    }
    __syncthreads();
    int c = t >> 2, kq = t & 3;
    int n = n0 + c;
    union { __hip_bfloat16 h[16]; uint4 u[2]; } pk;
    #pragma unroll
    for (int j = 0; j < 16; j++)
        pk.h[j] = __float2bfloat16(w[kq * 16 + j][c]);
    uint4* dst = (uint4*)(whb + (size_t)n * 64 + kq * 16);
    dst[0] = pk.u[0];
    dst[1] = pk.u[1];
}

// ---------------- head GEMM (bf16 MFMA) + bias + fused row sum-exp (R8 best) ----------------
__global__ __launch_bounds__(256) void k_head(
        const __hip_bfloat16* __restrict__ xfb, const __hip_bfloat16* __restrict__ whb,
        const float* __restrict__ bhead, float* __restrict__ out,
        float* __restrict__ wsum) {
    __shared__ float ssm[4][64];

    int i0 = blockIdx.x;
    int xcd = i0 & 7;
    int j  = i0 >> 3;
    int rb = j / CB_PER_XCD;
    int cb = xcd * CB_PER_XCD + (j - rb * CB_PER_XCD);

    int t = threadIdx.x;
    int w = t >> 6, l = t & 63;
    int lr = l & 15, lg = l >> 4;
    int r0 = rb * 64;
    int cw = cb * 256 + w * 64;
    int c4 = cw + lr * 4;

    bf16x8 a[4][2], b[4][2];
    {
        const __hip_bfloat16* ap = xfb + (size_t)(r0 + lr) * 64 + lg * 8;
        #pragma unroll
        for (int m = 0; m < 4; m++)
            #pragma unroll
            for (int ks = 0; ks < 2; ks++)
                a[m][ks] = *reinterpret_cast<const bf16x8*>(ap + m * 16 * 64 + ks * 32);
        const __hip_bfloat16* bp = whb + (size_t)c4 * 64 + lg * 8;
        #pragma unroll
        for (int n = 0; n < 4; n++)
            #pragma unroll
            for (int ks = 0; ks < 2; ks++)
                b[n][ks] = *reinterpret_cast<const bf16x8*>(bp + n * 64 + ks * 32);
    }

    f32x4 acc[4][4];
    #pragma unroll
    for (int m = 0; m < 4; m++)
        #pragma unroll
        for (int n = 0; n < 4; n++)
            #pragma unroll
            for (int j2 = 0; j2 < 4; j2++) acc[m][n][j2] = 0.f;

    #pragma unroll
    for (int ks = 0; ks < 2; ks++)
        #pragma unroll
        for (int m = 0; m < 4; m++)
            #pragma unroll
            for (int n = 0; n < 4; n++)
                acc[m][n] = __builtin_amdgcn_mfma_f32_16x16x32_bf16(a[m][ks], b[n][ks], acc[m][n], 0, 0, 0);

    bool all4 = (c4 + 3 < NV);
    float bias[4];
    bool  cok[4];
    if (all4) {
        float4 bv = *(const float4*)(bhead + c4);
        bias[0] = bv.x; bias[1] = bv.y; bias[2] = bv.z; bias[3] = bv.w;
        cok[0] = cok[1] = cok[2] = cok[3] = true;
    } else {
        #pragma unroll
        for (int n = 0; n < 4; n++) {
            int gc = c4 + n;
            cok[n] = (gc < NV);
            bias[n] = cok[n] ? bhead[gc] : 0.f;
        }
    }

    float es[16];
    #pragma unroll
    for (int m = 0; m < 4; m++) {
        #pragma unroll
        for (int i = 0; i < 4; i++) {
            int rl = 4 * lg + i;
            int grow = r0 + m * 16 + rl;
            float vals[4];
            float e = 0.f;
            #pragma unroll
            for (int n = 0; n < 4; n++) {
                float v = acc[m][n][i] + bias[n];
                vals[n] = v;
                if (cok[n]) e += __expf(v);
            }
            es[m * 4 + i] = e;
            float* dst = out + (size_t)grow * NV + c4;
            if (all4) {
                f32x4 vv = {vals[0], vals[1], vals[2], vals[3]};
                __builtin_nontemporal_store(vv, (f32x4*)dst);
            } else {
                #pragma unroll
                for (int n = 0; n < 4; n++)
                    if (cok[n]) __builtin_nontemporal_store(vals[n], dst + n);
            }
        }
    }

    #pragma unroll
    for (int m = 0; m < 4; m++) {
        #pragma unroll
        for (int i = 0; i < 4; i++) {
            float e = es[m * 4 + i];
            #pragma unroll
            for (int off = 1; off < 16; off <<= 1) e += __shfl_xor(e, off);
            if (lr == 0) ssm[w][m * 16 + 4 * lg + i] = e;
        }
    }

    __syncthreads();
    if (t < 64)
        wsum[cb * NN + r0 + t] = ssm[0][t] + ssm[1][t] + ssm[2][t] + ssm[3][t];
}

// ---------------- loss stage 1 ----------------
__global__ void k_loss1(const float* __restrict__ wsum,
                        const float* __restrict__ out, const int* __restrict__ targets,
                        float* __restrict__ lp) {
    int row = blockIdx.x * blockDim.x + threadIdx.x;
    if (row >= NN) return;
    float S = 0.f;
    for (int cb = 0; cb < NCB2; cb++)
        S += wsum[cb * NN + row];
    float lse = logf(S);
    int tg = targets[row];
    float lt = out[(size_t)row * NV + tg];
    lp[row] = lt - lse;
}

// ---------------- loss stage 2 ----------------
__global__ void k_loss2(const float* __restrict__ lp, float* __restrict__ out) {
    __shared__ float red[4];
    int t = threadIdx.x;
    float s = 0.f;
    for (int i = t; i < NN; i += 256) s += lp[i];
    for (int off = 1; off < 64; off <<= 1) s += __shfl_xor(s, off);
    if ((t & 63) == 0) red[t >> 6] = s;
    __syncthreads();
    if (t == 0) {
        float tot = red[0] + red[1] + red[2] + red[3];
        out[LOGITS] = -tot / (float)NN;
    }
}

extern "C" void kernel_launch(void* const* d_in, const int* in_sizes, int n_in,
                              void* d_out, int out_size, void* d_ws, size_t ws_size,
                              hipStream_t stream) {
    const int*   idx     = (const int*)d_in[0];
    const int*   targets = (const int*)d_in[1];
    const float* tok     = (const float*)d_in[2];
    const float* pos     = (const float*)d_in[3];
    const float* Wq      = (const float*)d_in[4];
    const float* Wk      = (const float*)d_in[5];
    const float* Wv      = (const float*)d_in[6];
    const float* Wo      = (const float*)d_in[7];
    const float* bo      = (const float*)d_in[8];
    const float* ln1g    = (const float*)d_in[9];
    const float* ln1b    = (const float*)d_in[10];
    const float* ln2g    = (const float*)d_in[11];
    const float* ln2b    = (const float*)d_in[12];
    const float* W1      = (const float*)d_in[13];
    const float* b1      = (const float*)d_in[14];
    const float* W2      = (const float*)d_in[15];
    const float* b2      = (const float*)d_in[16];
    const float* lnfg    = (const float*)d_in[17];
    const float* lnfb    = (const float*)d_in[18];
    const float* Wh      = (const float*)d_in[19];
    const float* bhead   = (const float*)d_in[20];

    float* ws = (float*)d_ws;
    float* x  = ws + X_OFF;
    __hip_bfloat16* q = (__hip_bfloat16*)(ws + Q_OFF);
    __hip_bfloat16* k = (__hip_bfloat16*)(ws + K_OFF);
    __hip_bfloat16* v = (__hip_bfloat16*)(ws + V_OFF);
    float* o  = ws + O_OFF;
    __hip_bfloat16* xfb = (__hip_bfloat16*)(ws + XFB_OFF);
    float* wsm = ws + WS2_OFF;
    __hip_bfloat16* whb = (__hip_bfloat16*)(ws + WHB_OFF);
    float* lp  = ws + LP_OFF;
    float* out = (float*)d_out;

    k_convW<<<NVP / 64, 256, 0, stream>>>(Wh, whb);

    k_ln_qkv<<<NN / 16, 256, 0, stream>>>(x, ln1g, ln1b, Wq, Wk, Wv, q, k, v,
                                          idx, tok, pos);

    for (int l = 0; l < NL; l++) {
        int last = (l == NL - 1) ? 1 : 0;
        int ln = last ? l : l + 1;
        k_attn<<<NB * NH * 4, 256, 0, stream>>>(q, k, v, o);
        k_post<<<NN / 8, 256, 0, stream>>>(o, Wo + l * ND * ND, bo + l * ND,
                                           ln2g + l * ND, ln2b + l * ND,
                                           W1 + l * ND * NF, b1 + l * NF,
                                           W2 + l * NF * ND, b2 + l * ND, x,
                                           ln1g + ln * ND, ln1b + ln * ND,
                                           Wq + ln * NH * ND * NHS,
                                           Wk + ln * NH * ND * NHS,
                                           Wv + ln * NH * ND * NHS,
                                           q, k, v,
                                           lnfg, lnfb, xfb, last);
    }

    k_head<<<NCB2 * RB_N, 256, 0, stream>>>(xfb, whb, bhead, out, wsm);

    k_loss1<<<NN / 256, 256, 0, stream>>>(wsm, out, targets, lp);
    k_loss2<<<1, 256, 0, stream>>>(lp, out);
}